// Round 1
// baseline (318.142 us; speedup 1.0000x reference)
//
#include <hip/hip_runtime.h>
#include <stdint.h>

typedef unsigned short u16;
typedef __attribute__((ext_vector_type(8))) short short8;
typedef __attribute__((ext_vector_type(4))) float floatx4;

#define NB 32
#define NC 256
#define NH 32
#define NW 32
#define NO 256
#define NPIX (NH*NW)     // 1024
#define KPIX 9
#define NG 9             // subarrays (groups)
#define RUN 32           // padded run length (per kernel-tap within group)
#define GK (NG*RUN)      // 288 k-slots per group
#define KTOT (NG*GK)     // 2592 total padded K
#define STR 40           // LDS row stride (elements) — 80B, 2-way-free frag reads

// ---------------- absmax reduction ----------------
__global__ void reduce_absmax4(const float4* __restrict__ p, int n4, unsigned* __restrict__ out) {
  float m = 0.f;
  for (int i = blockIdx.x * blockDim.x + threadIdx.x; i < n4; i += gridDim.x * blockDim.x) {
    float4 v = p[i];
    m = fmaxf(m, fmaxf(fmaxf(fabsf(v.x), fabsf(v.y)), fmaxf(fabsf(v.z), fabsf(v.w))));
  }
#pragma unroll
  for (int off = 32; off > 0; off >>= 1)
    m = fmaxf(m, __shfl_down(m, off, 64));
  __shared__ float sm[4];
  int lane = threadIdx.x & 63, wv = threadIdx.x >> 6;
  if (lane == 0) sm[wv] = m;
  __syncthreads();
  if (threadIdx.x == 0) {
    float mm = fmaxf(fmaxf(sm[0], sm[1]), fmaxf(sm[2], sm[3]));
    atomicMax(out, __float_as_uint(mm));
  }
}

// ---------------- quantize activations + transpose to [b][y][x][c] bf16 ----------------
// a_int = rint((x/s)*255) computed in f64 to match the numpy-f64 reference exactly.
__global__ void quant_act(const float* __restrict__ x, const unsigned* __restrict__ mx,
                          u16* __restrict__ qa) {
  __shared__ u16 t[32][33];
  double s = (double)__uint_as_float(*mx) + 1e-12;
  int tx = threadIdx.x & 31, ty = threadIdx.x >> 5;   // tx: x-coord / c-coord, ty: 0..7
  int ct = blockIdx.x, y = blockIdx.y, b = blockIdx.z;
#pragma unroll
  for (int j = 0; j < 4; j++) {
    int cl = ty + j * 8;
    float v = x[(((size_t)b * NC + ct * 32 + cl) * NH + y) * NW + tx];
    double q = rint(((double)v / s) * 255.0);
    float qf = (float)q;                       // integer, |q|<=255: exact in bf16
    t[cl][tx] = (u16)(__float_as_uint(qf) >> 16);
  }
  __syncthreads();
#pragma unroll
  for (int j = 0; j < 4; j++) {
    int xq = ty + j * 8;
    qa[(((size_t)b * NH + y) * NW + xq) * NC + ct * 32 + tx] = t[tx][xq];
  }
}

// ---------------- quantize weights + permute into padded-run K order ----------------
// k' = g*288 + r*32 + j ; c = (c_lo(g,r) & ~3) + j ; zero weight outside [c_lo, c_hi)
__global__ void quant_wt(const float* __restrict__ w, const unsigned* __restrict__ mw,
                         u16* __restrict__ wq, float* __restrict__ lossp) {
  double s = (double)__uint_as_float(*mw) + 1e-12;
  int idx = blockIdx.x * blockDim.x + threadIdx.x;
  if (idx == 0) *lossp = 0.0f;                  // a_loss output
  if (idx >= NO * KTOT) return;
  int o = idx / KTOT, kk = idx % KTOT;
  int g = kk / GK, rem = kk % GK;
  int r = rem / RUN, j = rem % RUN;
  int clo = (256 * g - r + 8) / 9;
  int chi = (256 * (g + 1) - r + 8) / 9; if (chi > NC) chi = NC;
  int cst = clo & ~3;
  int c = cst + j;
  float val = 0.f;
  if (c >= clo && c < chi) {
    float wv = w[((size_t)o * NC + c) * KPIX + r];
    val = (float)rint(((double)wv / s) * 15.0);   // |w_int| <= 15: exact in bf16
  }
  wq[idx] = (u16)(__float_as_uint(val) >> 16);
}

// ---------------- fused GEMM + per-group ADC ----------------
// D[m][n], m = b*1024 + y*32 + x (block = 4 image rows of one batch), n = o.
// K loop: 9 groups x 9 runs of 32; each run has uniform (dy,dx) and contiguous channels.
__global__ __launch_bounds__(256) void gemm_adc(const u16* __restrict__ qa,
                                                const u16* __restrict__ wq,
                                                const unsigned* __restrict__ sc,
                                                float* __restrict__ out) {
  __shared__ u16 lA[128 * STR];
  __shared__ u16 lB[128 * STR];
  const int tid = threadIdx.x;
  const int mblk = blockIdx.x, nblk = blockIdx.y;
  const int b = mblk >> 3;
  const int p0 = (mblk & 7) * 128;        // pixel base (4 rows of 32)
  const int n0 = nblk * 128;
  const int lane = tid & 63, wv = tid >> 6;
  const int wm = (wv & 1) * 64, wn = (wv >> 1) * 64;
  const int fm = lane & 15, fq = lane >> 4;

  double sa = (double)__uint_as_float(sc[0]) + 1e-12;
  double sw = (double)__uint_as_float(sc[1]) + 1e-12;
  // I/step = intsum * sa*sw*0.999 / (255*8*225*1e-3) = intsum * sa*sw*0.999/459
  double Sstep = sa * sw * 0.999 / 459.0;

  floatx4 acc[4][4];
  float tot[4][4][4];
#pragma unroll
  for (int mi = 0; mi < 4; mi++)
#pragma unroll
    for (int ni = 0; ni < 4; ni++)
#pragma unroll
      for (int rr = 0; rr < 4; rr++) { acc[mi][ni][rr] = 0.f; tot[mi][ni][rr] = 0.f; }

  for (int g = 0; g < NG; g++) {
#pragma unroll 1
    for (int r = 0; r < 9; r++) {
      const int dy = r / 3 - 1, dx = r % 3 - 1;
      const int clo = (256 * g - r + 8) / 9;
      const int cst = clo & ~3;
      // ---- stage A: 128 rows x 32k, 8B granularity (cst is 4-elem aligned) ----
#pragma unroll
      for (int i = 0; i < 4; i++) {
        int s = tid + i * 256;
        int row = s >> 3, j = s & 7;
        int p = p0 + row;
        int yy = (p >> 5) + dy, xx = (p & 31) + dx;
        uint2 v; v.x = 0u; v.y = 0u;
        if ((unsigned)yy < 32u && (unsigned)xx < 32u) {
          v = *(const uint2*)(qa + ((size_t)((b * NH + yy) * NW + xx)) * NC + cst + j * 4);
        }
        *(uint2*)&lA[row * STR + j * 4] = v;
      }
      // ---- stage B: 128 o-rows x 32k, 16B granularity ----
      const int kbase = g * GK + r * RUN;
#pragma unroll
      for (int i = 0; i < 2; i++) {
        int s = tid + i * 256;
        int row = s >> 2, q = s & 3;
        uint4 v = *(const uint4*)(wq + (size_t)(n0 + row) * KTOT + kbase + q * 8);
        *(uint4*)&lB[row * STR + q * 8] = v;
      }
      __syncthreads();
      // ---- one 32-K MFMA step: 4x4 tiles per wave ----
      short8 afr[4], bfr[4];
#pragma unroll
      for (int mi = 0; mi < 4; mi++)
        afr[mi] = *(const short8*)&lA[(wm + mi * 16 + fm) * STR + fq * 8];
#pragma unroll
      for (int ni = 0; ni < 4; ni++)
        bfr[ni] = *(const short8*)&lB[(wn + ni * 16 + fm) * STR + fq * 8];
#pragma unroll
      for (int mi = 0; mi < 4; mi++)
#pragma unroll
        for (int ni = 0; ni < 4; ni++)
          acc[mi][ni] = __builtin_amdgcn_mfma_f32_16x16x32_bf16(afr[mi], bfr[ni], acc[mi][ni], 0, 0, 0);
      __syncthreads();
    }
    // ---- ADC fold (exact integer accs -> f64 scale -> round/clip -> accumulate) ----
#pragma unroll
    for (int mi = 0; mi < 4; mi++)
#pragma unroll
      for (int ni = 0; ni < 4; ni++)
#pragma unroll
        for (int rr = 0; rr < 4; rr++) {
          double d = (double)acc[mi][ni][rr] * Sstep;
          double t = rint(d);
          t = fmin(fmax(t, -128.0), 127.0);
          tot[mi][ni][rr] += (float)t;
          acc[mi][ni][rr] = 0.f;
        }
  }
  // ---- epilogue: out[b][o][p] = tot * 1e-3 ; rows (fq*4+rr) are 4 consecutive pixels ----
#pragma unroll
  for (int mi = 0; mi < 4; mi++)
#pragma unroll
    for (int ni = 0; ni < 4; ni++) {
      int o = n0 + wn + ni * 16 + fm;
      int p = p0 + wm + mi * 16 + fq * 4;
      float4 o4;
      o4.x = tot[mi][ni][0] * 1e-3f;
      o4.y = tot[mi][ni][1] * 1e-3f;
      o4.z = tot[mi][ni][2] * 1e-3f;
      o4.w = tot[mi][ni][3] * 1e-3f;
      *(float4*)(out + ((size_t)(b * NO + o)) * NPIX + p) = o4;
    }
}

extern "C" void kernel_launch(void* const* d_in, const int* in_sizes, int n_in,
                              void* d_out, int out_size, void* d_ws, size_t ws_size,
                              hipStream_t stream) {
  const float* x = (const float*)d_in[0];
  const float* w = (const float*)d_in[1];
  float* out = (float*)d_out;

  unsigned* scal = (unsigned*)d_ws;
  u16* qa = (u16*)((char*)d_ws + 256);                 // (8388608 + 64) bf16 (+slack for run overread)
  u16* wq = (u16*)((char*)d_ws + 256 + 16777472);      // 256*2592 bf16

  hipMemsetAsync(d_ws, 0, 8, stream);                  // init the two absmax slots
  reduce_absmax4<<<1024, 256, 0, stream>>>((const float4*)x, (NB * NC * NH * NW) / 4, scal);
  reduce_absmax4<<<256, 256, 0, stream>>>((const float4*)w, (NO * NC * KPIX) / 4, scal + 1);
  quant_act<<<dim3(8, 32, 32), 256, 0, stream>>>(x, scal, qa);
  quant_wt<<<(NO * KTOT + 255) / 256, 256, 0, stream>>>(w, scal + 1, wq, out + (out_size - 1));
  gemm_adc<<<dim3(256, 2), 256, 0, stream>>>(qa, wq, scal, out);
}

// Round 2
// 229.033 us; speedup vs baseline: 1.3891x; 1.3891x over previous
//
#include <hip/hip_runtime.h>
#include <stdint.h>

typedef unsigned short u16;
typedef __attribute__((ext_vector_type(8))) short short8;
typedef __attribute__((ext_vector_type(4))) float floatx4;

#define NB 32
#define NC 256
#define NH 32
#define NW 32
#define NO 256
#define NPIX (NH*NW)     // 1024
#define KPIX 9
#define NG 9             // subarrays (groups)
#define RUN 32           // padded run length (per kernel-tap within group)
#define GK (NG*RUN)      // 288 k-slots per group
#define KTOT (NG*GK)     // 2592 total padded K
#define PADH 34
#define PADSP (PADH*PADH)       // 1156
#define QA_BSTRIDE (PADSP*NC)   // 295936 elems per batch

#define AS1 __attribute__((address_space(1)))
#define AS3 __attribute__((address_space(3)))

// ---------------- absmax reduction ----------------
__global__ void reduce_absmax4(const float4* __restrict__ p, int n4, unsigned* __restrict__ out) {
  float m = 0.f;
  for (int i = blockIdx.x * blockDim.x + threadIdx.x; i < n4; i += gridDim.x * blockDim.x) {
    float4 v = p[i];
    m = fmaxf(m, fmaxf(fmaxf(fabsf(v.x), fabsf(v.y)), fmaxf(fabsf(v.z), fabsf(v.w))));
  }
#pragma unroll
  for (int off = 32; off > 0; off >>= 1)
    m = fmaxf(m, __shfl_down(m, off, 64));
  __shared__ float sm[4];
  int lane = threadIdx.x & 63, wv = threadIdx.x >> 6;
  if (lane == 0) sm[wv] = m;
  __syncthreads();
  if (threadIdx.x == 0) {
    float mm = fmaxf(fmaxf(sm[0], sm[1]), fmaxf(sm[2], sm[3]));
    atomicMax(out, __float_as_uint(mm));
  }
}

// ---------------- quantize activations -> padded [b][y+1][x+1][c] bf16 ----------------
// a_int = rint((x/s)*255) in f64 — EXACT same math as the passing round-1 kernel.
__global__ void quant_act(const float* __restrict__ x, const unsigned* __restrict__ mx,
                          u16* __restrict__ qa) {
  __shared__ u16 t[32][33];
  double s = (double)__uint_as_float(*mx) + 1e-12;
  int tx = threadIdx.x & 31, ty = threadIdx.x >> 5;
  int ct = blockIdx.x, y = blockIdx.y, b = blockIdx.z;
#pragma unroll
  for (int j = 0; j < 4; j++) {
    int cl = ty + j * 8;
    float v = x[(((size_t)b * NC + ct * 32 + cl) * NH + y) * NW + tx];
    double q = rint(((double)v / s) * 255.0);
    float qf = (float)q;                       // integer, |q|<=255: exact in bf16
    t[cl][tx] = (u16)(__float_as_uint(qf) >> 16);
  }
  __syncthreads();
#pragma unroll
  for (int j = 0; j < 4; j++) {
    int xq = ty + j * 8;
    qa[((size_t)(b * PADH + y + 1) * PADH + (xq + 1)) * NC + ct * 32 + tx] = t[tx][xq];
  }
}

// ---------------- quantize weights + permute into padded-run K order ----------------
__global__ void quant_wt(const float* __restrict__ w, const unsigned* __restrict__ mw,
                         u16* __restrict__ wq, float* __restrict__ lossp) {
  double s = (double)__uint_as_float(*mw) + 1e-12;
  int idx = blockIdx.x * blockDim.x + threadIdx.x;
  if (idx == 0) *lossp = 0.0f;                  // a_loss output
  if (idx >= NO * KTOT) return;
  int o = idx / KTOT, kk = idx % KTOT;
  int g = kk / GK, rem = kk % GK;
  int r = rem / RUN, j = rem % RUN;
  int clo = (256 * g - r + 8) / 9;
  int chi = (256 * (g + 1) - r + 8) / 9; if (chi > NC) chi = NC;
  int cst = clo & ~3;
  int c = cst + j;
  float val = 0.f;
  if (c >= clo && c < chi) {
    float wv = w[((size_t)o * NC + c) * KPIX + r];
    val = (float)rint(((double)wv / s) * 15.0);
  }
  wq[idx] = (u16)(__float_as_uint(val) >> 16);
}

// ---------------- fused GEMM + per-group ADC ----------------
// 128x128 tile; 96-K (3-run) chunks staged direct-to-LDS via global_load_lds(16B).
// LDS layout [run][row][32ch]: 64B rows, lane-contiguous for the async copy.
__global__ __launch_bounds__(256) void gemm_adc(const u16* __restrict__ qa,
                                                const u16* __restrict__ wq,
                                                const unsigned* __restrict__ sc,
                                                float* __restrict__ out) {
  __shared__ u16 lA[3 * 128 * RUN];   // 24 KB
  __shared__ u16 lB[3 * 128 * RUN];   // 24 KB
  const int tid = threadIdx.x;
  const int mblk = blockIdx.x, nblk = blockIdx.y;
  const int b = mblk >> 3;
  const int p0 = (mblk & 7) * 128;        // pixel base (4 image rows of 32)
  const int n0 = nblk * 128;
  const int lane = tid & 63, wv = tid >> 6;
  const int wm = (wv & 1) * 64, wn = (wv >> 1) * 64;
  const int fm = lane & 15, fq = lane >> 4;

  double sa = (double)__uint_as_float(sc[0]) + 1e-12;
  double sw = (double)__uint_as_float(sc[1]) + 1e-12;
  double Sstep = sa * sw * 0.999 / 459.0;   // I/step = intsum * Sstep

  // per-thread staging constants: slot s = tid + i*256; run = i>>1 (wave-uniform per i)
  const u16* Ab[6]; const u16* Bb[6]; u16* Ad[6]; u16* Bd[6];
#pragma unroll
  for (int i = 0; i < 6; i++) {
    int s = tid + i * 256;
    int rowslot = s & 511;
    int row = rowslot >> 2, j = rowslot & 3;
    int p = p0 + row;
    int y = p >> 5, x = p & 31;
    Ab[i] = qa + (size_t)b * QA_BSTRIDE + ((y + 1) * PADH + (x + 1)) * NC + j * 8;
    Bb[i] = wq + (size_t)(n0 + row) * KTOT + j * 8;
    Ad[i] = &lA[s * 8];
    Bd[i] = &lB[s * 8];
  }

  floatx4 acc[4][4];
  float tot[4][4][4];
#pragma unroll
  for (int mi = 0; mi < 4; mi++)
#pragma unroll
    for (int ni = 0; ni < 4; ni++)
#pragma unroll
      for (int rr = 0; rr < 4; rr++) { acc[mi][ni][rr] = 0.f; tot[mi][ni][rr] = 0.f; }

#pragma unroll 1
  for (int g = 0; g < NG; g++) {
#pragma unroll 1
    for (int rc = 0; rc < 3; rc++) {
      int offA[3], offB[3];
#pragma unroll
      for (int ri = 0; ri < 3; ri++) {
        int r = rc * 3 + ri;
        int clo = (256 * g - r + 8) / 9;
        int cst = clo & ~3;
        offA[ri] = ((rc - 1) * PADH + (ri - 1)) * NC + cst;  // (dy*34+dx)*256 + cst
        offB[ri] = g * GK + r * RUN;
      }
#pragma unroll
      for (int i = 0; i < 6; i++)
        __builtin_amdgcn_global_load_lds((const AS1 void*)(Ab[i] + offA[i >> 1]),
                                         (AS3 void*)Ad[i], 16, 0, 0);
#pragma unroll
      for (int i = 0; i < 6; i++)
        __builtin_amdgcn_global_load_lds((const AS1 void*)(Bb[i] + offB[i >> 1]),
                                         (AS3 void*)Bd[i], 16, 0, 0);
      __syncthreads();
      // ---- 3 runs x 16 MFMA per wave ----
#pragma unroll
      for (int ri = 0; ri < 3; ri++) {
        short8 afr[4], bfr[4];
#pragma unroll
        for (int mi = 0; mi < 4; mi++)
          afr[mi] = *(const short8*)&lA[ri * 4096 + (wm + mi * 16 + fm) * RUN + fq * 8];
#pragma unroll
        for (int ni = 0; ni < 4; ni++)
          bfr[ni] = *(const short8*)&lB[ri * 4096 + (wn + ni * 16 + fm) * RUN + fq * 8];
#pragma unroll
        for (int mi = 0; mi < 4; mi++)
#pragma unroll
          for (int ni = 0; ni < 4; ni++)
            acc[mi][ni] = __builtin_amdgcn_mfma_f32_16x16x32_bf16(afr[mi], bfr[ni], acc[mi][ni], 0, 0, 0);
      }
      __syncthreads();
    }
    // ---- per-group ADC fold (f64 mul+rint exactly as before; clamp/accum in f32) ----
#pragma unroll
    for (int mi = 0; mi < 4; mi++)
#pragma unroll
      for (int ni = 0; ni < 4; ni++)
#pragma unroll
        for (int rr = 0; rr < 4; rr++) {
          double d = (double)acc[mi][ni][rr] * Sstep;
          float tf = (float)rint(d);
          tf = fminf(fmaxf(tf, -128.f), 127.f);
          tot[mi][ni][rr] += tf;
          acc[mi][ni][rr] = 0.f;
        }
  }
  // ---- epilogue ----
#pragma unroll
  for (int mi = 0; mi < 4; mi++)
#pragma unroll
    for (int ni = 0; ni < 4; ni++) {
      int o = n0 + wn + ni * 16 + fm;
      int p = p0 + wm + mi * 16 + fq * 4;
      float4 o4;
      o4.x = tot[mi][ni][0] * 1e-3f;
      o4.y = tot[mi][ni][1] * 1e-3f;
      o4.z = tot[mi][ni][2] * 1e-3f;
      o4.w = tot[mi][ni][3] * 1e-3f;
      *(float4*)(out + ((size_t)(b * NO + o)) * NPIX + p) = o4;
    }
}

extern "C" void kernel_launch(void* const* d_in, const int* in_sizes, int n_in,
                              void* d_out, int out_size, void* d_ws, size_t ws_size,
                              hipStream_t stream) {
  const float* x = (const float*)d_in[0];
  const float* w = (const float*)d_in[1];
  float* out = (float*)d_out;

  unsigned* scal = (unsigned*)d_ws;
  u16* qa = (u16*)((char*)d_ws + 256);                       // padded acts: 18,939,904 B
  // 8 KB slack after qa_pad absorbs the worst-case staging tail overread (~4.1 KB)
  u16* wq = (u16*)((char*)d_ws + 256 + 18939904 + 8192);     // weights: 1,327,104 B

  // one memset covers scalars + qa_pad borders + slack
  hipMemsetAsync(d_ws, 0, 256 + 18939904 + 8192, stream);
  reduce_absmax4<<<1024, 256, 0, stream>>>((const float4*)x, (NB * NC * NH * NW) / 4, scal);
  reduce_absmax4<<<256, 256, 0, stream>>>((const float4*)w, (NO * NC * KPIX) / 4, scal + 1);
  quant_act<<<dim3(8, 32, 32), 256, 0, stream>>>(x, scal, qa);
  quant_wt<<<(NO * KTOT + 255) / 256, 256, 0, stream>>>(w, scal + 1, wq, out + (out_size - 1));
  gemm_adc<<<dim3(256, 2), 256, 0, stream>>>(qa, wq, scal, out);
}

// Round 3
// 186.096 us; speedup vs baseline: 1.7096x; 1.2307x over previous
//
#include <hip/hip_runtime.h>
#include <stdint.h>

typedef unsigned short u16;
typedef __attribute__((ext_vector_type(8))) short short8;
typedef __attribute__((ext_vector_type(4))) float floatx4;

#define NB 32
#define NC 256
#define NH 32
#define NW 32
#define NO 256
#define NPIX (NH*NW)     // 1024
#define KPIX 9
#define NG 9             // subarrays (groups)
#define RUN 32           // padded run length (per kernel-tap within group)
#define GK (NG*RUN)      // 288 k-slots per group
#define KTOT (NG*GK)     // 2592 total padded K
#define PADH 34
#define PADSP (PADH*PADH)       // 1156
#define QA_BSTRIDE (PADSP*NC)   // 295936 elems per batch

#define AS1 __attribute__((address_space(1)))
#define AS3 __attribute__((address_space(3)))

// ---------------- absmax reduction ----------------
__global__ void reduce_absmax4(const float4* __restrict__ p, int n4, unsigned* __restrict__ out) {
  float m = 0.f;
  for (int i = blockIdx.x * blockDim.x + threadIdx.x; i < n4; i += gridDim.x * blockDim.x) {
    float4 v = p[i];
    m = fmaxf(m, fmaxf(fmaxf(fabsf(v.x), fabsf(v.y)), fmaxf(fabsf(v.z), fabsf(v.w))));
  }
#pragma unroll
  for (int off = 32; off > 0; off >>= 1)
    m = fmaxf(m, __shfl_down(m, off, 64));
  __shared__ float sm[4];
  int lane = threadIdx.x & 63, wv = threadIdx.x >> 6;
  if (lane == 0) sm[wv] = m;
  __syncthreads();
  if (threadIdx.x == 0) {
    float mm = fmaxf(fmaxf(sm[0], sm[1]), fmaxf(sm[2], sm[3]));
    atomicMax(out, __float_as_uint(mm));
  }
}

// ---------------- zero the halo borders of the padded activation tensor ----------------
// border pixels per batch: rows y=0,33 (full 34) + cols x=0,33 for y=1..32 -> 132 pixels.
// each thread zeroes 16 u16 (one pixel is 256 u16 = 16 threads).
__global__ void zero_pad(u16* __restrict__ qa) {
  int idx = blockIdx.x * blockDim.x + threadIdx.x;   // 32*132*16 = 67584 threads
  int b = idx >> 11;            // 132*16 = 2112 per batch
  int rem = idx & 2047;
  if (rem >= 2112) return;
  int pb = rem >> 4, c16 = rem & 15;
  int y, x;
  if (pb < 68) { y = (pb >= 34) ? 33 : 0; x = pb % 34; }
  else { int q = pb - 68; y = 1 + (q >> 1); x = (q & 1) ? 33 : 0; }
  uint4 z; z.x = z.y = z.z = z.w = 0u;
  *(uint4*)(qa + ((size_t)(b * PADH + y) * PADH + x) * NC + c16 * 16) = z;
}

// ---------------- quantize activations -> padded [b][y+1][x+1][c] bf16 ----------------
// a_int = rint((x/s)*255) in f64 — EXACT same math as the passing round-1/2 kernels.
__global__ void quant_act(const float* __restrict__ x, const unsigned* __restrict__ mx,
                          u16* __restrict__ qa) {
  __shared__ u16 t[32][33];
  double s = (double)__uint_as_float(*mx) + 1e-12;
  int tx = threadIdx.x & 31, ty = threadIdx.x >> 5;
  int ct = blockIdx.x, y = blockIdx.y, b = blockIdx.z;
#pragma unroll
  for (int j = 0; j < 4; j++) {
    int cl = ty + j * 8;
    float v = x[(((size_t)b * NC + ct * 32 + cl) * NH + y) * NW + tx];
    double q = rint(((double)v / s) * 255.0);
    float qf = (float)q;                       // integer, |q|<=255: exact in bf16
    t[cl][tx] = (u16)(__float_as_uint(qf) >> 16);
  }
  __syncthreads();
#pragma unroll
  for (int j = 0; j < 4; j++) {
    int xq = ty + j * 8;
    qa[((size_t)(b * PADH + y + 1) * PADH + (xq + 1)) * NC + ct * 32 + tx] = t[tx][xq];
  }
}

// ---------------- quantize weights + permute into padded-run K order ----------------
__global__ void quant_wt(const float* __restrict__ w, const unsigned* __restrict__ mw,
                         u16* __restrict__ wq, float* __restrict__ lossp) {
  double s = (double)__uint_as_float(*mw) + 1e-12;
  int idx = blockIdx.x * blockDim.x + threadIdx.x;
  if (idx == 0) *lossp = 0.0f;                  // a_loss output
  if (idx >= NO * KTOT) return;
  int o = idx / KTOT, kk = idx % KTOT;
  int g = kk / GK, rem = kk % GK;
  int r = rem / RUN, j = rem % RUN;
  int clo = (256 * g - r + 8) / 9;
  int chi = (256 * (g + 1) - r + 8) / 9; if (chi > NC) chi = NC;
  int cst = clo & ~3;
  int c = cst + j;
  float val = 0.f;
  if (c >= clo && c < chi) {
    float wv = w[((size_t)o * NC + c) * KPIX + r];
    val = (float)rint(((double)wv / s) * 15.0);
  }
  wq[idx] = (u16)(__float_as_uint(val) >> 16);
}

// ---------------- fused GEMM + per-group ADC ----------------
// 128x64 tile; grid (256,4)=1024 blocks -> 4 blocks/CU co-resident.
// 96-K (3-run) chunks staged direct-to-LDS via global_load_lds(16B).
__global__ __launch_bounds__(256, 4) void gemm_adc(const u16* __restrict__ qa,
                                                   const u16* __restrict__ wq,
                                                   const unsigned* __restrict__ sc,
                                                   float* __restrict__ out) {
  __shared__ u16 lA[3 * 128 * RUN];   // 24 KB
  __shared__ u16 lB[3 * 64 * RUN];    // 12 KB
  const int tid = threadIdx.x;
  const int mblk = blockIdx.x, nblk = blockIdx.y;
  const int b = mblk >> 3;
  const int p0 = (mblk & 7) * 128;        // pixel base (4 image rows of 32)
  const int n0 = nblk * 64;
  const int lane = tid & 63, wv = tid >> 6;
  const int wm = (wv & 1) * 64, wn = (wv >> 1) * 32;
  const int fm = lane & 15, fq = lane >> 4;

  double sa = (double)__uint_as_float(sc[0]) + 1e-12;
  double sw = (double)__uint_as_float(sc[1]) + 1e-12;
  double Sstep = sa * sw * 0.999 / 459.0;   // I/step = intsum * Sstep

  // A staging: slot s = tid + i*256 (i=0..5); run = i>>1; 4 lanes per 128-pixel row
  const u16* Ab[6]; u16* Ad[6];
#pragma unroll
  for (int i = 0; i < 6; i++) {
    int s = tid + i * 256;
    int rowslot = s & 511;
    int row = rowslot >> 2, j = rowslot & 3;
    int p = p0 + row;
    int y = p >> 5, x = p & 31;
    Ab[i] = qa + (size_t)b * QA_BSTRIDE + ((y + 1) * PADH + (x + 1)) * NC + j * 8;
    Ad[i] = &lA[s * 8];
  }
  // B staging: one instr per run; row = tid>>2, j = tid&3
  const u16* Bb = wq + (size_t)(n0 + (tid >> 2)) * KTOT + (tid & 3) * 8;
  u16* Bd0 = &lB[tid * 8];

  floatx4 acc[4][2];
  float tot[4][2][4];
#pragma unroll
  for (int mi = 0; mi < 4; mi++)
#pragma unroll
    for (int ni = 0; ni < 2; ni++)
#pragma unroll
      for (int rr = 0; rr < 4; rr++) { acc[mi][ni][rr] = 0.f; tot[mi][ni][rr] = 0.f; }

#pragma unroll 1
  for (int g = 0; g < NG; g++) {
#pragma unroll 1
    for (int rc = 0; rc < 3; rc++) {
      int offA[3], offB[3];
#pragma unroll
      for (int ri = 0; ri < 3; ri++) {
        int r = rc * 3 + ri;
        int clo = (256 * g - r + 8) / 9;
        int cst = clo & ~3;
        offA[ri] = ((rc - 1) * PADH + (ri - 1)) * NC + cst;  // (dy*34+dx)*256 + cst
        offB[ri] = g * GK + r * RUN;
      }
#pragma unroll
      for (int i = 0; i < 6; i++)
        __builtin_amdgcn_global_load_lds((const AS1 void*)(Ab[i] + offA[i >> 1]),
                                         (AS3 void*)Ad[i], 16, 0, 0);
#pragma unroll
      for (int i = 0; i < 3; i++)
        __builtin_amdgcn_global_load_lds((const AS1 void*)(Bb + offB[i]),
                                         (AS3 void*)(Bd0 + i * 2048 * 8 / 8), 16, 0, 0);
      __syncthreads();
      // ---- 3 runs x 8 MFMA per wave ----
#pragma unroll
      for (int ri = 0; ri < 3; ri++) {
        short8 afr[4], bfr[2];
#pragma unroll
        for (int mi = 0; mi < 4; mi++)
          afr[mi] = *(const short8*)&lA[ri * 4096 + (wm + mi * 16 + fm) * RUN + fq * 8];
#pragma unroll
        for (int ni = 0; ni < 2; ni++)
          bfr[ni] = *(const short8*)&lB[ri * 2048 + (wn + ni * 16 + fm) * RUN + fq * 8];
#pragma unroll
        for (int mi = 0; mi < 4; mi++)
#pragma unroll
          for (int ni = 0; ni < 2; ni++)
            acc[mi][ni] = __builtin_amdgcn_mfma_f32_16x16x32_bf16(afr[mi], bfr[ni], acc[mi][ni], 0, 0, 0);
      }
      __syncthreads();
    }
    // ---- per-group ADC fold (f64 mul+rint EXACTLY as the passing kernel) ----
#pragma unroll
    for (int mi = 0; mi < 4; mi++)
#pragma unroll
      for (int ni = 0; ni < 2; ni++)
#pragma unroll
        for (int rr = 0; rr < 4; rr++) {
          double d = (double)acc[mi][ni][rr] * Sstep;
          float tf = (float)rint(d);
          tf = fminf(fmaxf(tf, -128.f), 127.f);
          tot[mi][ni][rr] += tf;
          acc[mi][ni][rr] = 0.f;
        }
  }
  // ---- epilogue ----
#pragma unroll
  for (int mi = 0; mi < 4; mi++)
#pragma unroll
    for (int ni = 0; ni < 2; ni++) {
      int o = n0 + wn + ni * 16 + fm;
      int p = p0 + wm + mi * 16 + fq * 4;
      float4 o4;
      o4.x = tot[mi][ni][0] * 1e-3f;
      o4.y = tot[mi][ni][1] * 1e-3f;
      o4.z = tot[mi][ni][2] * 1e-3f;
      o4.w = tot[mi][ni][3] * 1e-3f;
      *(float4*)(out + ((size_t)(b * NO + o)) * NPIX + p) = o4;
    }
}

extern "C" void kernel_launch(void* const* d_in, const int* in_sizes, int n_in,
                              void* d_out, int out_size, void* d_ws, size_t ws_size,
                              hipStream_t stream) {
  const float* x = (const float*)d_in[0];
  const float* w = (const float*)d_in[1];
  float* out = (float*)d_out;

  unsigned* scal = (unsigned*)d_ws;
  u16* qa = (u16*)((char*)d_ws + 256);                       // padded acts: 18,939,904 B
  // 8 KB slack after qa absorbs staging tail overread; 0xAA poison is finite bf16 and
  // always multiplies against zero weight pad slots -> no zeroing needed there.
  u16* wq = (u16*)((char*)d_ws + 256 + 18939904 + 8192);     // weights: 1,327,104 B

  hipMemsetAsync(d_ws, 0, 256, stream);                      // absmax slots only
  reduce_absmax4<<<1024, 256, 0, stream>>>((const float4*)x, (NB * NC * NH * NW) / 4, scal);
  reduce_absmax4<<<256, 256, 0, stream>>>((const float4*)w, (NO * NC * KPIX) / 4, scal + 1);
  zero_pad<<<(32 * 2048 + 255) / 256, 256, 0, stream>>>(qa);
  quant_act<<<dim3(8, 32, 32), 256, 0, stream>>>(x, scal, qa);
  quant_wt<<<(NO * KTOT + 255) / 256, 256, 0, stream>>>(w, scal + 1, wq, out + (out_size - 1));
  gemm_adc<<<dim3(256, 4), 256, 0, stream>>>(qa, wq, scal, out);
}

// Round 4
// 185.834 us; speedup vs baseline: 1.7120x; 1.0014x over previous
//
#include <hip/hip_runtime.h>
#include <stdint.h>

typedef unsigned short u16;
typedef __attribute__((ext_vector_type(8))) short short8;
typedef __attribute__((ext_vector_type(4))) float floatx4;

#define NB 32
#define NC 256
#define NH 32
#define NW 32
#define NO 256
#define NPIX (NH*NW)     // 1024
#define KPIX 9
#define NG 9             // subarrays (groups)
#define RUN 32           // padded run length (per kernel-tap within group)
#define GK (NG*RUN)      // 288 k-slots per group
#define KTOT (NG*GK)     // 2592 total padded K
#define PADH 34
#define PADSP (PADH*PADH)       // 1156
#define QA_BSTRIDE (PADSP*NC)   // 295936 elems per batch

#define AS1 __attribute__((address_space(1)))
#define AS3 __attribute__((address_space(3)))

// ---------------- absmax reduction ----------------
__global__ void reduce_absmax4(const float4* __restrict__ p, int n4, unsigned* __restrict__ out) {
  float m = 0.f;
  for (int i = blockIdx.x * blockDim.x + threadIdx.x; i < n4; i += gridDim.x * blockDim.x) {
    float4 v = p[i];
    m = fmaxf(m, fmaxf(fmaxf(fabsf(v.x), fabsf(v.y)), fmaxf(fabsf(v.z), fabsf(v.w))));
  }
#pragma unroll
  for (int off = 32; off > 0; off >>= 1)
    m = fmaxf(m, __shfl_down(m, off, 64));
  __shared__ float sm[4];
  int lane = threadIdx.x & 63, wv = threadIdx.x >> 6;
  if (lane == 0) sm[wv] = m;
  __syncthreads();
  if (threadIdx.x == 0) {
    float mm = fmaxf(fmaxf(sm[0], sm[1]), fmaxf(sm[2], sm[3]));
    atomicMax(out, __float_as_uint(mm));
  }
}

// ---------------- zero the halo borders of the padded activation tensor ----------------
__global__ void zero_pad(u16* __restrict__ qa) {
  int idx = blockIdx.x * blockDim.x + threadIdx.x;   // 32*2112 slots in 32*2048-grid steps
  int b = idx >> 11;
  int rem = idx & 2047;
  if (rem >= 2112) return;
  int pb = rem >> 4, c16 = rem & 15;
  int y, x;
  if (pb < 68) { y = (pb >= 34) ? 33 : 0; x = pb % 34; }
  else { int q = pb - 68; y = 1 + (q >> 1); x = (q & 1) ? 33 : 0; }
  uint4 z; z.x = z.y = z.z = z.w = 0u;
  *(uint4*)(qa + ((size_t)(b * PADH + y) * PADH + x) * NC + c16 * 16) = z;
}

// ---------------- quantize activations -> padded [b][y+1][x+1][c] bf16 ----------------
// a_int = rint((x/s)*255) in f64 — EXACT same math as all passing rounds.
__global__ void quant_act(const float* __restrict__ x, const unsigned* __restrict__ mx,
                          u16* __restrict__ qa) {
  __shared__ u16 t[32][33];
  double s = (double)__uint_as_float(*mx) + 1e-12;
  int tx = threadIdx.x & 31, ty = threadIdx.x >> 5;
  int ct = blockIdx.x, y = blockIdx.y, b = blockIdx.z;
#pragma unroll
  for (int j = 0; j < 4; j++) {
    int cl = ty + j * 8;
    float v = x[(((size_t)b * NC + ct * 32 + cl) * NH + y) * NW + tx];
    double q = rint(((double)v / s) * 255.0);
    float qf = (float)q;                       // integer, |q|<=255: exact in bf16
    t[cl][tx] = (u16)(__float_as_uint(qf) >> 16);
  }
  __syncthreads();
#pragma unroll
  for (int j = 0; j < 4; j++) {
    int xq = ty + j * 8;
    qa[((size_t)(b * PADH + y + 1) * PADH + (xq + 1)) * NC + ct * 32 + tx] = t[tx][xq];
  }
}

// ---------------- quantize weights + permute into padded-run K order ----------------
__global__ void quant_wt(const float* __restrict__ w, const unsigned* __restrict__ mw,
                         u16* __restrict__ wq, float* __restrict__ lossp) {
  double s = (double)__uint_as_float(*mw) + 1e-12;
  int idx = blockIdx.x * blockDim.x + threadIdx.x;
  if (idx == 0) *lossp = 0.0f;                  // a_loss output
  if (idx >= NO * KTOT) return;
  int o = idx / KTOT, kk = idx % KTOT;
  int g = kk / GK, rem = kk % GK;
  int r = rem / RUN, j = rem % RUN;
  int clo = (256 * g - r + 8) / 9;
  int chi = (256 * (g + 1) - r + 8) / 9; if (chi > NC) chi = NC;
  int cst = clo & ~3;
  int c = cst + j;
  float val = 0.f;
  if (c >= clo && c < chi) {
    float wv = w[((size_t)o * NC + c) * KPIX + r];
    val = (float)rint(((double)wv / s) * 15.0);
  }
  wq[idx] = (u16)(__float_as_uint(val) >> 16);
}

// ---------------- fused GEMM + per-group ADC ----------------
// 128x64 block tile, 128 threads (2 waves x 64x64 tiles), grid (256,4)=1024 blocks
// -> 4 blocks/CU. 96-K chunks staged direct-to-LDS (16B async) with a
// source-side swizzle: LDS slot (row, j') holds global k-word (j'-(row>>1))&3,
// so frag reads at j' = (fq + ((fm>>1)&3))&3 hit 8 bank-quads x2 (conflict-free).
__global__ __launch_bounds__(128, 2) void gemm_adc(const u16* __restrict__ qa,
                                                   const u16* __restrict__ wq,
                                                   const unsigned* __restrict__ sc,
                                                   float* __restrict__ out) {
  __shared__ u16 lA[3 * 128 * RUN];   // 24 KB
  __shared__ u16 lB[3 * 64 * RUN];    // 12 KB
  const int tid = threadIdx.x;
  const int mblk = blockIdx.x, nblk = blockIdx.y;
  const int b = mblk >> 3;
  const int p0 = (mblk & 7) * 128;        // pixel base (4 image rows of 32)
  const int n0 = nblk * 64;
  const int lane = tid & 63, w = tid >> 6;
  const int fm = lane & 15, fq = lane >> 4;
  const int swz = (fq + ((fm >> 1) & 3)) & 3;

  double sa = (double)__uint_as_float(sc[0]) + 1e-12;
  double sw = (double)__uint_as_float(sc[1]) + 1e-12;
  double Sstep = sa * sw * 0.999 / 459.0;   // I/step = intsum * Sstep

  // staging constants: slot s = tid + ii*128; row = (tid>>2)+ii*32; j' = tid&3
  // global k-word jsrc = (j' - (row>>1)) & 3 = ((tid&3) - ((tid>>3)&3)) & 3
  const int r0 = tid >> 2;
  const int jsrc = ((tid & 3) - ((tid >> 3) & 3)) & 3;
  const u16* Abase = qa + (size_t)b * QA_BSTRIDE
                     + (((p0 >> 5) + 1) * PADH + (r0 + 1)) * NC + jsrc * 8;
  const u16* Bbase = wq + (size_t)(n0 + r0) * KTOT + jsrc * 8;
  u16* Adst = &lA[tid * 8];
  u16* Bdst = &lB[tid * 8];

  floatx4 acc[4][4];
  float tot[4][4][4];
#pragma unroll
  for (int mi = 0; mi < 4; mi++)
#pragma unroll
    for (int ni = 0; ni < 4; ni++)
#pragma unroll
      for (int rr = 0; rr < 4; rr++) { acc[mi][ni][rr] = 0.f; tot[mi][ni][rr] = 0.f; }

#pragma unroll 1
  for (int g = 0; g < NG; g++) {
#pragma unroll 1
    for (int rc = 0; rc < 3; rc++) {
      int offA[3], kb[3];
#pragma unroll
      for (int ri = 0; ri < 3; ri++) {
        int r = rc * 3 + ri;
        int cst = ((256 * g - r + 8) / 9) & ~3;
        offA[ri] = ((rc - 1) * PADH + (ri - 1)) * NC + cst;  // (dy*34+dx)*256 + cst
        kb[ri] = g * GK + r * RUN;
      }
      // A: 12 async 16B loads (3 runs x 4 row-quarters)
#pragma unroll
      for (int ri = 0; ri < 3; ri++)
#pragma unroll
        for (int ii = 0; ii < 4; ii++)
          __builtin_amdgcn_global_load_lds(
              (const AS1 void*)(Abase + offA[ri] + ii * (PADH * NC)),
              (AS3 void*)(Adst + ri * 4096 + ii * 1024), 16, 0, 0);
      // B: 6 async 16B loads (3 runs x 2 row-halves)
#pragma unroll
      for (int ii = 0; ii < 6; ii++)
        __builtin_amdgcn_global_load_lds(
            (const AS1 void*)(Bbase + (ii & 1) * 32 * KTOT + kb[ii >> 1]),
            (AS3 void*)(Bdst + ii * 1024), 16, 0, 0);
      __syncthreads();
      // ---- 3 runs x 16 MFMA per wave ----
#pragma unroll
      for (int ri = 0; ri < 3; ri++) {
        short8 afr[4], bfr[4];
#pragma unroll
        for (int mi = 0; mi < 4; mi++)
          afr[mi] = *(const short8*)&lA[ri * 4096 + (w * 64 + mi * 16 + fm) * RUN + swz * 8];
#pragma unroll
        for (int ni = 0; ni < 4; ni++)
          bfr[ni] = *(const short8*)&lB[ri * 2048 + (ni * 16 + fm) * RUN + swz * 8];
#pragma unroll
        for (int mi = 0; mi < 4; mi++)
#pragma unroll
          for (int ni = 0; ni < 4; ni++)
            acc[mi][ni] = __builtin_amdgcn_mfma_f32_16x16x32_bf16(afr[mi], bfr[ni], acc[mi][ni], 0, 0, 0);
      }
      __syncthreads();
    }
    // ---- per-group ADC fold (f64 mul+rint EXACTLY as the passing kernels) ----
#pragma unroll
    for (int mi = 0; mi < 4; mi++)
#pragma unroll
      for (int ni = 0; ni < 4; ni++)
#pragma unroll
        for (int rr = 0; rr < 4; rr++) {
          double d = (double)acc[mi][ni][rr] * Sstep;
          float tf = (float)rint(d);
          tf = fminf(fmaxf(tf, -128.f), 127.f);
          tot[mi][ni][rr] += tf;
          acc[mi][ni][rr] = 0.f;
        }
  }
  // ---- epilogue ----
#pragma unroll
  for (int mi = 0; mi < 4; mi++)
#pragma unroll
    for (int ni = 0; ni < 4; ni++) {
      int o = n0 + ni * 16 + fm;
      int p = p0 + w * 64 + mi * 16 + fq * 4;
      float4 o4;
      o4.x = tot[mi][ni][0] * 1e-3f;
      o4.y = tot[mi][ni][1] * 1e-3f;
      o4.z = tot[mi][ni][2] * 1e-3f;
      o4.w = tot[mi][ni][3] * 1e-3f;
      *(float4*)(out + ((size_t)(b * NO + o)) * NPIX + p) = o4;
    }
}

extern "C" void kernel_launch(void* const* d_in, const int* in_sizes, int n_in,
                              void* d_out, int out_size, void* d_ws, size_t ws_size,
                              hipStream_t stream) {
  const float* x = (const float*)d_in[0];
  const float* w = (const float*)d_in[1];
  float* out = (float*)d_out;

  unsigned* scal = (unsigned*)d_ws;
  u16* qa = (u16*)((char*)d_ws + 256);                       // padded acts: 18,939,904 B
  u16* wq = (u16*)((char*)d_ws + 256 + 18939904 + 8192);     // weights: 1,327,104 B

  hipMemsetAsync(d_ws, 0, 256, stream);                      // absmax slots only
  reduce_absmax4<<<1024, 256, 0, stream>>>((const float4*)x, (NB * NC * NH * NW) / 4, scal);
  reduce_absmax4<<<256, 256, 0, stream>>>((const float4*)w, (NO * NC * KPIX) / 4, scal + 1);
  zero_pad<<<(32 * 2048 + 255) / 256, 256, 0, stream>>>(qa);
  quant_act<<<dim3(8, 32, 32), 256, 0, stream>>>(x, scal, qa);
  quant_wt<<<(NO * KTOT + 255) / 256, 256, 0, stream>>>(w, scal + 1, wq, out + (out_size - 1));
  gemm_adc<<<dim3(256, 4), 128, 0, stream>>>(qa, wq, scal, out);
}

// Round 5
// 182.414 us; speedup vs baseline: 1.7441x; 1.0187x over previous
//
#include <hip/hip_runtime.h>
#include <stdint.h>

typedef unsigned short u16;
typedef __attribute__((ext_vector_type(8))) short short8;
typedef __attribute__((ext_vector_type(4))) float floatx4;

#define NB 32
#define NC 256
#define NH 32
#define NW 32
#define NO 256
#define NPIX (NH*NW)     // 1024
#define KPIX 9
#define NG 9             // subarrays (groups)
#define RUN 32           // padded run length (per kernel-tap within group)
#define GK (NG*RUN)      // 288 k-slots per group
#define KTOT (NG*GK)     // 2592 total padded K
#define PADH 34
#define PADSP (PADH*PADH)       // 1156
#define QA_BSTRIDE (PADSP*NC)   // 295936 elems per batch

#define AS1 __attribute__((address_space(1)))
#define AS3 __attribute__((address_space(3)))

// ---------------- fused: absmax(x), absmax(w), zero qa halo borders ----------------
// blocks [0,1024): absmax x ; [1024,1088): absmax w ; [1088,1376): border zeroing
__global__ void fused_pre(const float4* __restrict__ x4, int nx4,
                          const float4* __restrict__ w4, int nw4,
                          unsigned* __restrict__ outx, unsigned* __restrict__ outw,
                          u16* __restrict__ qa) {
  int bid = blockIdx.x;
  if (bid >= 1088) {
    // ---- zero halo borders: 32 batches x 132 border pixels x 256 ch ----
    int zb = bid - 1088;              // 0..287 ; 9 blocks per batch
    int b = zb / 9;
    int rem = (zb % 9) * 256 + threadIdx.x;   // 0..2303, need <2112 (132 px * 16 ch-groups)
    if (rem >= 2112) return;
    int pb = rem >> 4, c16 = rem & 15;
    int y, x;
    if (pb < 68) { y = (pb >= 34) ? 33 : 0; x = pb % 34; }
    else { int q = pb - 68; y = 1 + (q >> 1); x = (q & 1) ? 33 : 0; }
    uint4 z; z.x = z.y = z.z = z.w = 0u;
    *(uint4*)(qa + ((size_t)(b * PADH + y) * PADH + x) * NC + c16 * 16) = z;
    return;
  }
  const float4* p; int n4; unsigned* out; int nb, b0;
  if (bid < 1024) { p = x4; n4 = nx4; out = outx; nb = 1024; b0 = bid; }
  else            { p = w4; n4 = nw4; out = outw; nb = 64;   b0 = bid - 1024; }
  float m = 0.f;
  for (int i = b0 * blockDim.x + threadIdx.x; i < n4; i += nb * blockDim.x) {
    float4 v = p[i];
    m = fmaxf(m, fmaxf(fmaxf(fabsf(v.x), fabsf(v.y)), fmaxf(fabsf(v.z), fabsf(v.w))));
  }
#pragma unroll
  for (int off = 32; off > 0; off >>= 1)
    m = fmaxf(m, __shfl_down(m, off, 64));
  __shared__ float sm[4];
  int lane = threadIdx.x & 63, wv = threadIdx.x >> 6;
  if (lane == 0) sm[wv] = m;
  __syncthreads();
  if (threadIdx.x == 0) {
    float mm = fmaxf(fmaxf(sm[0], sm[1]), fmaxf(sm[2], sm[3]));
    atomicMax(out, __float_as_uint(mm));
  }
}

// ---------------- quantize activations -> padded [b][y+1][x+1][c] bf16 ----------------
// a_int = rint(x * (255/s)) in f64 (== rint(x/s*255) to within 2 f64 ulp).
__global__ void quant_act(const float* __restrict__ x, const unsigned* __restrict__ mx,
                          u16* __restrict__ qa) {
  __shared__ u16 t[32][33];
  double s = (double)__uint_as_float(*mx) + 1e-12;
  double inv = 255.0 / s;
  int tx = threadIdx.x & 31, ty = threadIdx.x >> 5;
  int ct = blockIdx.x, y = blockIdx.y, b = blockIdx.z;
#pragma unroll
  for (int j = 0; j < 4; j++) {
    int cl = ty + j * 8;
    float v = x[(((size_t)b * NC + ct * 32 + cl) * NH + y) * NW + tx];
    double q = rint((double)v * inv);
    float qf = (float)q;                       // integer, |q|<=255: exact in bf16
    t[cl][tx] = (u16)(__float_as_uint(qf) >> 16);
  }
  __syncthreads();
#pragma unroll
  for (int j = 0; j < 4; j++) {
    int xq = ty + j * 8;
    qa[((size_t)(b * PADH + y + 1) * PADH + (xq + 1)) * NC + ct * 32 + tx] = t[tx][xq];
  }
}

// ---------------- quantize weights + permute into padded-run K order ----------------
__global__ void quant_wt(const float* __restrict__ w, const unsigned* __restrict__ mw,
                         u16* __restrict__ wq, float* __restrict__ lossp) {
  double s = (double)__uint_as_float(*mw) + 1e-12;
  double inv = 15.0 / s;
  int idx = blockIdx.x * blockDim.x + threadIdx.x;
  if (idx == 0) *lossp = 0.0f;                  // a_loss output
  if (idx >= NO * KTOT) return;
  int o = idx / KTOT, kk = idx % KTOT;
  int g = kk / GK, rem = kk % GK;
  int r = rem / RUN, j = rem % RUN;
  int clo = (256 * g - r + 8) / 9;
  int chi = (256 * (g + 1) - r + 8) / 9; if (chi > NC) chi = NC;
  int cst = clo & ~3;
  int c = cst + j;
  float val = 0.f;
  if (c >= clo && c < chi) {
    float wv = w[((size_t)o * NC + c) * KPIX + r];
    val = (float)rint((double)wv * inv);
  }
  wq[idx] = (u16)(__float_as_uint(val) >> 16);
}

// ---------------- fused GEMM + per-group ADC ----------------
// 128x64 block tile, 128 threads (2 waves x 64x64), 1024 blocks = 4/CU.
// XCD-aware swizzle: XCD = L%8 owns 32 contiguous m-tiles x all 4 n-tiles ->
// B fully L2-resident per XCD, A halo re-reads become L2 hits (was L3-BW-bound).
__global__ __launch_bounds__(128, 2) void gemm_adc(const u16* __restrict__ qa,
                                                   const u16* __restrict__ wq,
                                                   const unsigned* __restrict__ sc,
                                                   float* __restrict__ out) {
  __shared__ u16 lA[3 * 128 * RUN];   // 24 KB
  __shared__ u16 lB[3 * 64 * RUN];    // 12 KB
  const int tid = threadIdx.x;
  const int L = blockIdx.x;
  const int ss = L >> 3;
  const int mblk = (L & 7) * 32 + (ss >> 2);   // XCD-major m-tiling
  const int nblk = ss & 3;
  const int b = mblk >> 3;
  const int p0 = (mblk & 7) * 128;        // pixel base (4 image rows of 32)
  const int n0 = nblk * 64;
  const int lane = tid & 63, w = tid >> 6;
  const int fm = lane & 15, fq = lane >> 4;
  const int swz = (fq + ((fm >> 1) & 3)) & 3;

  double sa = (double)__uint_as_float(sc[0]) + 1e-12;
  double sw = (double)__uint_as_float(sc[1]) + 1e-12;
  double Sstep = sa * sw * 0.999 / 459.0;   // I/step = intsum * Sstep

  // staging constants: slot s = tid + ii*128; row = (tid>>2)+ii*32; j' = tid&3
  // global k-word jsrc = (j' - (row>>1)) & 3 = ((tid&3) - ((tid>>3)&3)) & 3
  const int r0 = tid >> 2;
  const int jsrc = ((tid & 3) - ((tid >> 3) & 3)) & 3;
  const u16* Abase = qa + (size_t)b * QA_BSTRIDE
                     + (((p0 >> 5) + 1) * PADH + (r0 + 1)) * NC + jsrc * 8;
  const u16* Bbase = wq + (size_t)(n0 + r0) * KTOT + jsrc * 8;
  u16* Adst = &lA[tid * 8];
  u16* Bdst = &lB[tid * 8];

  floatx4 acc[4][4];
  float tot[4][4][4];
#pragma unroll
  for (int mi = 0; mi < 4; mi++)
#pragma unroll
    for (int ni = 0; ni < 4; ni++)
#pragma unroll
      for (int rr = 0; rr < 4; rr++) { acc[mi][ni][rr] = 0.f; tot[mi][ni][rr] = 0.f; }

#pragma unroll 1
  for (int g = 0; g < NG; g++) {
#pragma unroll 1
    for (int rc = 0; rc < 3; rc++) {
      int offA[3], kb[3];
#pragma unroll
      for (int ri = 0; ri < 3; ri++) {
        int r = rc * 3 + ri;
        int cst = ((256 * g - r + 8) / 9) & ~3;
        offA[ri] = ((rc - 1) * PADH + (ri - 1)) * NC + cst;  // (dy*34+dx)*256 + cst
        kb[ri] = g * GK + r * RUN;
      }
      // A: 12 async 16B loads (3 runs x 4 row-quarters)
#pragma unroll
      for (int ri = 0; ri < 3; ri++)
#pragma unroll
        for (int ii = 0; ii < 4; ii++)
          __builtin_amdgcn_global_load_lds(
              (const AS1 void*)(Abase + offA[ri] + ii * (PADH * NC)),
              (AS3 void*)(Adst + ri * 4096 + ii * 1024), 16, 0, 0);
      // B: 6 async 16B loads (3 runs x 2 row-halves)
#pragma unroll
      for (int ii = 0; ii < 6; ii++)
        __builtin_amdgcn_global_load_lds(
            (const AS1 void*)(Bbase + (ii & 1) * 32 * KTOT + kb[ii >> 1]),
            (AS3 void*)(Bdst + ii * 1024), 16, 0, 0);
      __syncthreads();
      // ---- 3 runs x 16 MFMA per wave ----
#pragma unroll
      for (int ri = 0; ri < 3; ri++) {
        short8 afr[4], bfr[4];
#pragma unroll
        for (int mi = 0; mi < 4; mi++)
          afr[mi] = *(const short8*)&lA[ri * 4096 + (w * 64 + mi * 16 + fm) * RUN + swz * 8];
#pragma unroll
        for (int ni = 0; ni < 4; ni++)
          bfr[ni] = *(const short8*)&lB[ri * 2048 + (ni * 16 + fm) * RUN + swz * 8];
#pragma unroll
        for (int mi = 0; mi < 4; mi++)
#pragma unroll
          for (int ni = 0; ni < 4; ni++)
            acc[mi][ni] = __builtin_amdgcn_mfma_f32_16x16x32_bf16(afr[mi], bfr[ni], acc[mi][ni], 0, 0, 0);
      }
      __syncthreads();
    }
    // ---- per-group ADC fold (f64 mul+rint EXACTLY as the passing kernels) ----
#pragma unroll
    for (int mi = 0; mi < 4; mi++)
#pragma unroll
      for (int ni = 0; ni < 4; ni++)
#pragma unroll
        for (int rr = 0; rr < 4; rr++) {
          double d = (double)acc[mi][ni][rr] * Sstep;
          float tf = (float)rint(d);
          tf = fminf(fmaxf(tf, -128.f), 127.f);
          tot[mi][ni][rr] += tf;
          acc[mi][ni][rr] = 0.f;
        }
  }
  // ---- epilogue ----
#pragma unroll
  for (int mi = 0; mi < 4; mi++)
#pragma unroll
    for (int ni = 0; ni < 4; ni++) {
      int o = n0 + ni * 16 + fm;
      int p = p0 + w * 64 + mi * 16 + fq * 4;
      float4 o4;
      o4.x = tot[mi][ni][0] * 1e-3f;
      o4.y = tot[mi][ni][1] * 1e-3f;
      o4.z = tot[mi][ni][2] * 1e-3f;
      o4.w = tot[mi][ni][3] * 1e-3f;
      *(float4*)(out + ((size_t)(b * NO + o)) * NPIX + p) = o4;
    }
}

extern "C" void kernel_launch(void* const* d_in, const int* in_sizes, int n_in,
                              void* d_out, int out_size, void* d_ws, size_t ws_size,
                              hipStream_t stream) {
  const float* x = (const float*)d_in[0];
  const float* w = (const float*)d_in[1];
  float* out = (float*)d_out;

  unsigned* scal = (unsigned*)d_ws;
  u16* qa = (u16*)((char*)d_ws + 256);                       // padded acts: 18,939,904 B
  u16* wq = (u16*)((char*)d_ws + 256 + 18939904 + 8192);     // weights: 1,327,104 B

  hipMemsetAsync(d_ws, 0, 256, stream);                      // absmax slots only
  fused_pre<<<1376, 256, 0, stream>>>((const float4*)x, (NB * NC * NH * NW) / 4,
                                      (const float4*)w, (NO * NC * KPIX) / 4,
                                      scal, scal + 1, qa);
  quant_act<<<dim3(8, 32, 32), 256, 0, stream>>>(x, scal, qa);
  quant_wt<<<(NO * KTOT + 255) / 256, 256, 0, stream>>>(w, scal + 1, wq, out + (out_size - 1));
  gemm_adc<<<1024, 128, 0, stream>>>(qa, wq, scal, out);
}

// Round 6
// 176.957 us; speedup vs baseline: 1.7978x; 1.0308x over previous
//
#include <hip/hip_runtime.h>
#include <stdint.h>

typedef unsigned short u16;
typedef __attribute__((ext_vector_type(8))) short short8;
typedef __attribute__((ext_vector_type(4))) float floatx4;

#define NB 32
#define NC 256
#define NH 32
#define NW 32
#define NO 256
#define NPIX (NH*NW)     // 1024
#define KPIX 9
#define NG 9             // subarrays (groups)
#define RUN 32           // padded run length (per kernel-tap within group)
#define GK (NG*RUN)      // 288 k-slots per group
#define KTOT (NG*GK)     // 2592 total padded K
#define PADH 34
#define PADSP (PADH*PADH)       // 1156
#define QA_BSTRIDE (PADSP*NC)   // 295936 elems per batch

#define AS1 __attribute__((address_space(1)))
#define AS3 __attribute__((address_space(3)))

// ---------------- fused: absmax(x), absmax(w), zero qa halo borders ----------------
// blocks [0,1024): absmax x ; [1024,1088): absmax w ; [1088,1376): border zeroing
__global__ void fused_pre(const float4* __restrict__ x4, int nx4,
                          const float4* __restrict__ w4, int nw4,
                          unsigned* __restrict__ outx, unsigned* __restrict__ outw,
                          u16* __restrict__ qa) {
  int bid = blockIdx.x;
  if (bid >= 1088) {
    // ---- zero halo borders: 32 batches x 132 border pixels x 256 ch ----
    int zb = bid - 1088;              // 0..287 ; 9 blocks per batch
    int b = zb / 9;
    int rem = (zb % 9) * 256 + threadIdx.x;   // need <2112 (132 px * 16 ch-groups)
    if (rem >= 2112) return;
    int pb = rem >> 4, c16 = rem & 15;
    int y, x;
    if (pb < 68) { y = (pb >= 34) ? 33 : 0; x = pb % 34; }
    else { int q = pb - 68; y = 1 + (q >> 1); x = (q & 1) ? 33 : 0; }
    uint4 z; z.x = z.y = z.z = z.w = 0u;
    *(uint4*)(qa + ((size_t)(b * PADH + y) * PADH + x) * NC + c16 * 16) = z;
    return;
  }
  const float4* p; int n4; unsigned* out; int nb, b0;
  if (bid < 1024) { p = x4; n4 = nx4; out = outx; nb = 1024; b0 = bid; }
  else            { p = w4; n4 = nw4; out = outw; nb = 64;   b0 = bid - 1024; }
  float m = 0.f;
  for (int i = b0 * blockDim.x + threadIdx.x; i < n4; i += nb * blockDim.x) {
    float4 v = p[i];
    m = fmaxf(m, fmaxf(fmaxf(fabsf(v.x), fabsf(v.y)), fmaxf(fabsf(v.z), fabsf(v.w))));
  }
#pragma unroll
  for (int off = 32; off > 0; off >>= 1)
    m = fmaxf(m, __shfl_down(m, off, 64));
  __shared__ float sm[4];
  int lane = threadIdx.x & 63, wv = threadIdx.x >> 6;
  if (lane == 0) sm[wv] = m;
  __syncthreads();
  if (threadIdx.x == 0) {
    float mm = fmaxf(fmaxf(sm[0], sm[1]), fmaxf(sm[2], sm[3]));
    atomicMax(out, __float_as_uint(mm));
  }
}

// ---------------- fused quantization: acts (blocks <8192) + weights ----------------
// act: a_int = rint(x * (255/s)) in f64, -> padded [b][y+1][x+1][c] bf16.
// wt:  w_int = rint(w * (15/s)) in f64, permuted into padded-run K order.
// Math identical to the passing round-5 kernels.
__global__ void fused_quant(const float* __restrict__ x, const float* __restrict__ w,
                            const unsigned* __restrict__ scal,
                            u16* __restrict__ qa, u16* __restrict__ wq,
                            float* __restrict__ lossp) {
  int bid = blockIdx.x;
  if (bid < 8192) {
    __shared__ u16 t[32][33];
    double s = (double)__uint_as_float(scal[0]) + 1e-12;
    double inv = 255.0 / s;
    int tx = threadIdx.x & 31, ty = threadIdx.x >> 5;
    int ct = bid & 7, y = (bid >> 3) & 31, b = bid >> 8;
#pragma unroll
    for (int j = 0; j < 4; j++) {
      int cl = ty + j * 8;
      float v = x[(((size_t)b * NC + ct * 32 + cl) * NH + y) * NW + tx];
      double q = rint((double)v * inv);
      float qf = (float)q;                       // integer, |q|<=255: exact in bf16
      t[cl][tx] = (u16)(__float_as_uint(qf) >> 16);
    }
    __syncthreads();
#pragma unroll
    for (int j = 0; j < 4; j++) {
      int xq = ty + j * 8;
      qa[((size_t)(b * PADH + y + 1) * PADH + (xq + 1)) * NC + ct * 32 + tx] = t[tx][xq];
    }
    return;
  }
  // ---- weights: 2592 blocks cover NO*KTOT = 663552 elems ----
  double s = (double)__uint_as_float(scal[1]) + 1e-12;
  double inv = 15.0 / s;
  int idx = (bid - 8192) * blockDim.x + threadIdx.x;
  if (idx == 0) *lossp = 0.0f;                  // a_loss output
  if (idx >= NO * KTOT) return;
  int o = idx / KTOT, kk = idx % KTOT;
  int g = kk / GK, rem = kk % GK;
  int r = rem / RUN, j = rem % RUN;
  int clo = (256 * g - r + 8) / 9;
  int chi = (256 * (g + 1) - r + 8) / 9; if (chi > NC) chi = NC;
  int cst = clo & ~3;
  int c = cst + j;
  float val = 0.f;
  if (c >= clo && c < chi) {
    float wv = w[((size_t)o * NC + c) * KPIX + r];
    val = (float)rint((double)wv * inv);
  }
  wq[idx] = (u16)(__float_as_uint(val) >> 16);
}

// ---------------- fused GEMM + per-group ADC ----------------
// 128x64 block tile, 128 threads (2 waves x 64x64 tiles), grid (256,4)=1024 blocks
// -> 4 blocks/CU. 96-K chunks staged direct-to-LDS (16B async) with a
// source-side swizzle: LDS slot (row, j') holds global k-word (j'-(row>>1))&3,
// so frag reads at j' = (fq + ((fm>>1)&3))&3 hit 8 bank-quads x2 (conflict-free).
// NOTE: round-5's XCD swizzle regressed (95 vs 83 us) -> natural block order here.
__global__ __launch_bounds__(128, 2) void gemm_adc(const u16* __restrict__ qa,
                                                   const u16* __restrict__ wq,
                                                   const unsigned* __restrict__ sc,
                                                   float* __restrict__ out) {
  __shared__ u16 lA[3 * 128 * RUN];   // 24 KB
  __shared__ u16 lB[3 * 64 * RUN];    // 12 KB
  const int tid = threadIdx.x;
  const int mblk = blockIdx.x, nblk = blockIdx.y;
  const int b = mblk >> 3;
  const int p0 = (mblk & 7) * 128;        // pixel base (4 image rows of 32)
  const int n0 = nblk * 64;
  const int lane = tid & 63, w = tid >> 6;
  const int fm = lane & 15, fq = lane >> 4;
  const int swz = (fq + ((fm >> 1) & 3)) & 3;

  double sa = (double)__uint_as_float(sc[0]) + 1e-12;
  double sw = (double)__uint_as_float(sc[1]) + 1e-12;
  double Sstep = sa * sw * 0.999 / 459.0;   // I/step = intsum * Sstep

  // staging constants: slot s = tid + ii*128; row = (tid>>2)+ii*32; j' = tid&3
  // global k-word jsrc = (j' - (row>>1)) & 3 = ((tid&3) - ((tid>>3)&3)) & 3
  const int r0 = tid >> 2;
  const int jsrc = ((tid & 3) - ((tid >> 3) & 3)) & 3;
  const u16* Abase = qa + (size_t)b * QA_BSTRIDE
                     + (((p0 >> 5) + 1) * PADH + (r0 + 1)) * NC + jsrc * 8;
  const u16* Bbase = wq + (size_t)(n0 + r0) * KTOT + jsrc * 8;
  u16* Adst = &lA[tid * 8];
  u16* Bdst = &lB[tid * 8];

  floatx4 acc[4][4];
  float tot[4][4][4];
#pragma unroll
  for (int mi = 0; mi < 4; mi++)
#pragma unroll
    for (int ni = 0; ni < 4; ni++)
#pragma unroll
      for (int rr = 0; rr < 4; rr++) { acc[mi][ni][rr] = 0.f; tot[mi][ni][rr] = 0.f; }

#pragma unroll 1
  for (int g = 0; g < NG; g++) {
#pragma unroll 1
    for (int rc = 0; rc < 3; rc++) {
      int offA[3], kb[3];
#pragma unroll
      for (int ri = 0; ri < 3; ri++) {
        int r = rc * 3 + ri;
        int cst = ((256 * g - r + 8) / 9) & ~3;
        offA[ri] = ((rc - 1) * PADH + (ri - 1)) * NC + cst;  // (dy*34+dx)*256 + cst
        kb[ri] = g * GK + r * RUN;
      }
      // A: 12 async 16B loads (3 runs x 4 row-quarters)
#pragma unroll
      for (int ri = 0; ri < 3; ri++)
#pragma unroll
        for (int ii = 0; ii < 4; ii++)
          __builtin_amdgcn_global_load_lds(
              (const AS1 void*)(Abase + offA[ri] + ii * (PADH * NC)),
              (AS3 void*)(Adst + ri * 4096 + ii * 1024), 16, 0, 0);
      // B: 6 async 16B loads (3 runs x 2 row-halves)
#pragma unroll
      for (int ii = 0; ii < 6; ii++)
        __builtin_amdgcn_global_load_lds(
            (const AS1 void*)(Bbase + (ii & 1) * 32 * KTOT + kb[ii >> 1]),
            (AS3 void*)(Bdst + ii * 1024), 16, 0, 0);
      __syncthreads();
      // ---- 3 runs x 16 MFMA per wave ----
#pragma unroll
      for (int ri = 0; ri < 3; ri++) {
        short8 afr[4], bfr[4];
#pragma unroll
        for (int mi = 0; mi < 4; mi++)
          afr[mi] = *(const short8*)&lA[ri * 4096 + (w * 64 + mi * 16 + fm) * RUN + swz * 8];
#pragma unroll
        for (int ni = 0; ni < 4; ni++)
          bfr[ni] = *(const short8*)&lB[ri * 2048 + (ni * 16 + fm) * RUN + swz * 8];
#pragma unroll
        for (int mi = 0; mi < 4; mi++)
#pragma unroll
          for (int ni = 0; ni < 4; ni++)
            acc[mi][ni] = __builtin_amdgcn_mfma_f32_16x16x32_bf16(afr[mi], bfr[ni], acc[mi][ni], 0, 0, 0);
      }
      __syncthreads();
    }
    // ---- per-group ADC fold (f64 mul+rint EXACTLY as the passing kernels) ----
#pragma unroll
    for (int mi = 0; mi < 4; mi++)
#pragma unroll
      for (int ni = 0; ni < 4; ni++)
#pragma unroll
        for (int rr = 0; rr < 4; rr++) {
          double d = (double)acc[mi][ni][rr] * Sstep;
          float tf = (float)rint(d);
          tf = fminf(fmaxf(tf, -128.f), 127.f);
          tot[mi][ni][rr] += tf;
          acc[mi][ni][rr] = 0.f;
        }
  }
  // ---- epilogue ----
#pragma unroll
  for (int mi = 0; mi < 4; mi++)
#pragma unroll
    for (int ni = 0; ni < 4; ni++) {
      int o = n0 + ni * 16 + fm;
      int p = p0 + w * 64 + mi * 16 + fq * 4;
      float4 o4;
      o4.x = tot[mi][ni][0] * 1e-3f;
      o4.y = tot[mi][ni][1] * 1e-3f;
      o4.z = tot[mi][ni][2] * 1e-3f;
      o4.w = tot[mi][ni][3] * 1e-3f;
      *(float4*)(out + ((size_t)(b * NO + o)) * NPIX + p) = o4;
    }
}

extern "C" void kernel_launch(void* const* d_in, const int* in_sizes, int n_in,
                              void* d_out, int out_size, void* d_ws, size_t ws_size,
                              hipStream_t stream) {
  const float* x = (const float*)d_in[0];
  const float* w = (const float*)d_in[1];
  float* out = (float*)d_out;

  unsigned* scal = (unsigned*)d_ws;
  u16* qa = (u16*)((char*)d_ws + 256);                       // padded acts: 18,939,904 B
  u16* wq = (u16*)((char*)d_ws + 256 + 18939904 + 8192);     // weights: 1,327,104 B

  hipMemsetAsync(d_ws, 0, 256, stream);                      // absmax slots only
  fused_pre<<<1376, 256, 0, stream>>>((const float4*)x, (NB * NC * NH * NW) / 4,
                                      (const float4*)w, (NO * NC * KPIX) / 4,
                                      scal, scal + 1, qa);
  fused_quant<<<8192 + 2592, 256, 0, stream>>>(x, w, scal, qa, wq, out + (out_size - 1));
  gemm_adc<<<dim3(256, 4), 128, 0, stream>>>(qa, wq, scal, out);
}